// Round 8
// baseline (134.540 us; speedup 1.0000x reference)
//
#include <hip/hip_runtime.h>
#include <math.h>

// Problem constants
#define B_    1024
#define D_    768
#define C_    150
#define P_    64
#define TWOD  1536
#define NCLS  151   // C+1
#define CPAD  256   // partial row: 0..150 logits, 151..191 junk, 192..255 u

// fused_tile: 128b x 64c per block, 8x4/thr, e split 16 ways
#define ECHUNKS 16
#define ECHUNK  96

// gemm v2: 64x64 tile, BK=64, double-buffered LDS, stride 72 halves
#define GSTR  72
#define GBUF  (64 * GSTR)      // halves per buffer
#define NKT   (D_ / 64)        // 12 k-iterations
// u-path LDS stride (halves)
#define USTRU 120
// pair phase LDS stride (halves)
#define USTR  72
// fused xT padded stride (words/ep): row b at offset b + (b>>3)*4
#define XSTR  192

// persistent grid
#define NBLK  512

// Workspace layout (float offsets)
#define OFF_MH      0
#define OFF_XH      (OFF_MH + (C_ * TWOD) / 2)
#define OFF_PARTIAL (OFF_XH + (B_ * TWOD) / 2)
#define OFF_UHF     (OFF_PARTIAL + ECHUNKS * B_ * CPAD)
#define OFF_SQN     (OFF_UHF + (B_ * P_) / 2)
#define OFF_CLS     (OFF_SQN + B_)
#define OFF_PAIR    (OFF_CLS + B_)

typedef __bf16    bfx8   __attribute__((ext_vector_type(8)));
typedef _Float16  fp16x8 __attribute__((ext_vector_type(8)));
typedef _Float16  h2v    __attribute__((ext_vector_type(2)));
typedef float     f32x4  __attribute__((ext_vector_type(4)));

// ---------------------------------------------------------------------------
// Persistent sync state (device globals: zero-init at load, survive graph
// replay, NOT poisoned by the harness workspace fill). Monotonic protocol:
// g_gen counts barriers ever completed (3 per launch now); G0 read at entry.
// g_flag[456]: per-gemm-task completion flags for dataflow B->C overlap —
// set to G0+1 when that task's xh/mh tile is at the coherence point.
// ---------------------------------------------------------------------------
__device__ int g_arr[8 * 16];    // 8 arrival-counter lines, 64B-spaced
__device__ int g_gen[32 * 16];   // 32 replicated gen lines
__device__ int g_flag[456];      // gemm tile flags (monotonic epochs)

__device__ inline ushort f2bf(float f) {
    union { float f; unsigned u; } c; c.f = f;
    unsigned r = c.u + 0x7fffu + ((c.u >> 16) & 1u);
    return (ushort)(r >> 16);
}
__device__ inline ushort f2h(float f) {
    _Float16 h = (_Float16)f;
    return __builtin_bit_cast(ushort, h);
}
// pack 8 fp32 -> 8 bf16 in a uint4
__device__ inline uint4 pack_bf8(float4 a, float4 b) {
    uint4 r;
    r.x = (unsigned)f2bf(a.x) | ((unsigned)f2bf(a.y) << 16);
    r.y = (unsigned)f2bf(a.z) | ((unsigned)f2bf(a.w) << 16);
    r.z = (unsigned)f2bf(b.x) | ((unsigned)f2bf(b.y) << 16);
    r.w = (unsigned)f2bf(b.z) | ((unsigned)f2bf(b.w) << 16);
    return r;
}
// pack 8 fp32 -> 8 f16 in a uint4
__device__ inline uint4 pack_h8(float4 a, float4 b) {
    uint4 r;
    r.x = (unsigned)f2h(a.x) | ((unsigned)f2h(a.y) << 16);
    r.y = (unsigned)f2h(a.z) | ((unsigned)f2h(a.w) << 16);
    r.z = (unsigned)f2h(b.x) | ((unsigned)f2h(b.y) << 16);
    r.w = (unsigned)f2h(b.z) | ((unsigned)f2h(b.w) << 16);
    return r;
}
__device__ inline unsigned addrelu2(unsigned a, unsigned m) {
    h2v s = __builtin_bit_cast(h2v, a) + __builtin_bit_cast(h2v, m);
    h2v z = {(_Float16)0.f, (_Float16)0.f};
    s = __builtin_elementwise_max(s, z);
    return __builtin_bit_cast(unsigned, s);
}
__device__ inline unsigned relu2(unsigned a) {
    h2v s = __builtin_bit_cast(h2v, a);
    h2v z = {(_Float16)0.f, (_Float16)0.f};
    s = __builtin_elementwise_max(s, z);
    return __builtin_bit_cast(unsigned, s);
}
__device__ inline float dot2acc(unsigned a, unsigned b, float c) {
    return __builtin_amdgcn_fdot2(__builtin_bit_cast(h2v, a),
                                  __builtin_bit_cast(h2v, b), c, false);
}

// ---------------------------------------------------------------------------
// Write-through stores (sc0 sc1): agent-visible at the coherence point once
// vmcnt-complete (validated v5-v7: absmax 0 with fence-free readers).
// ---------------------------------------------------------------------------
__device__ __forceinline__ void st_wt_u16(ushort* p, unsigned v) {
    asm volatile("global_store_short %0, %1, off sc0 sc1"
                 :: "v"(p), "v"(v) : "memory");
}
__device__ __forceinline__ void st_wt_f32(float* p, float v) {
    asm volatile("global_store_dword %0, %1, off sc0 sc1"
                 :: "v"(p), "v"(v) : "memory");
}
__device__ __forceinline__ void st_wt_f32x4(float* p, f32x4 v) {
    asm volatile("global_store_dwordx4 %0, %1, off sc0 sc1"
                 :: "v"(p), "v"(v) : "memory");
}

// ---------------------------------------------------------------------------
// Grid barrier (monotonic, zero cache maintenance, ~2-3us class).
// ---------------------------------------------------------------------------
__device__ __forceinline__ void grid_barrier(int G0, int b)
{
    asm volatile("s_waitcnt vmcnt(0)" ::: "memory");
    __syncthreads();
    if (threadIdx.x == 0) {
        const int target = G0 + b;
        __hip_atomic_fetch_add(&g_arr[(blockIdx.x & 7) * 16], 1,
                               __ATOMIC_RELAXED, __HIP_MEMORY_SCOPE_AGENT);
        if (blockIdx.x == 0) {
            const int starget = NBLK * target;
            for (;;) {
                int s = 0;
#pragma unroll
                for (int k = 0; k < 8; ++k)
                    s += __hip_atomic_load(&g_arr[k * 16], __ATOMIC_RELAXED,
                                           __HIP_MEMORY_SCOPE_AGENT);
                if (s - starget >= 0) break;
                __builtin_amdgcn_s_sleep(1);
            }
#pragma unroll
            for (int r = 0; r < 32; ++r)
                __hip_atomic_store(&g_gen[r * 16], target, __ATOMIC_RELAXED,
                                   __HIP_MEMORY_SCOPE_AGENT);
        } else {
            int* myg = &g_gen[(blockIdx.x & 31) * 16];
            while (__hip_atomic_load(myg, __ATOMIC_RELAXED,
                                     __HIP_MEMORY_SCOPE_AGENT) - target < 0)
                __builtin_amdgcn_s_sleep(4);
        }
        asm volatile("" ::: "memory");
    }
    __syncthreads();
}

// ---------------------------------------------------------------------------
// Phase B: merged MFMA GEMM (64x64, BK=64, dbuf LDS). After its stores reach
// the coherence point, publishes g_flag[id] = G0+1 (dataflow B->C overlap).
// ---------------------------------------------------------------------------
__device__ __forceinline__ void phase_gemm(
    int id, int G0, char* smemc,
    const float* __restrict__ x, const float* __restrict__ mem,
    const float* __restrict__ fc_w, const float* __restrict__ fc_b,
    ushort* __restrict__ xh, ushort* __restrict__ mh)
{
    if (id >= 456) return;
    ushort* As = (ushort*)smemc;                       // 2 x 64 x GSTR
    ushort* Bs = (ushort*)(smemc + 2 * GBUF * 2);      // 2 x 64 x GSTR
    const int t = threadIdx.x;

    const float* A; ushort* Out; int M, m0, n0, koff; bool xblk;
    if (id < 384) {
        xblk = true;  A = x;    Out = xh; M = B_;
        m0 = (id & 15) * 64; n0 = (id >> 4) * 64; koff = 0;
    } else {
        int q = id - 384;
        xblk = false; A = mem;  Out = mh; M = C_;
        m0 = (q % 3) * 64; n0 = (q / 3) * 64; koff = D_;
    }

    const int wave = t >> 6, lane = t & 63;
    const int wm = wave * 16;
    const int fm = lane & 15, quad = lane >> 4;

    const int row_a = t >> 2, qa = (t & 3) * 16;
    const int ar = min(m0 + row_a, M - 1);
    const float* Arow = A + (size_t)ar * D_ + qa;
    const float* Brow = fc_w + (size_t)(n0 + row_a) * TWOD + koff + qa;
    const int lw = row_a * GSTR + qa;

    f32x4 acc[4];
#pragma unroll
    for (int j = 0; j < 4; ++j) {
        float bv = xblk ? fc_b[n0 + j * 16 + fm] : 0.f;
        acc[j] = (f32x4){bv, bv, bv, bv};
    }

    float4 pa0 = *(const float4*)(Arow);
    float4 pa1 = *(const float4*)(Arow + 4);
    float4 pa2 = *(const float4*)(Arow + 8);
    float4 pa3 = *(const float4*)(Arow + 12);
    float4 pb0 = *(const float4*)(Brow);
    float4 pb1 = *(const float4*)(Brow + 4);
    float4 pb2 = *(const float4*)(Brow + 8);
    float4 pb3 = *(const float4*)(Brow + 12);

    for (int kt = 0; kt < NKT; ++kt) {
        ushort* Ad = As + (kt & 1) * GBUF;
        ushort* Bd = Bs + (kt & 1) * GBUF;
        *(uint4*)&Ad[lw]     = pack_bf8(pa0, pa1);
        *(uint4*)&Ad[lw + 8] = pack_bf8(pa2, pa3);
        *(uint4*)&Bd[lw]     = pack_bf8(pb0, pb1);
        *(uint4*)&Bd[lw + 8] = pack_bf8(pb2, pb3);
        __syncthreads();
        if (kt + 1 < NKT) {
            const int k1 = (kt + 1) * 64;
            pa0 = *(const float4*)(Arow + k1);
            pa1 = *(const float4*)(Arow + k1 + 4);
            pa2 = *(const float4*)(Arow + k1 + 8);
            pa3 = *(const float4*)(Arow + k1 + 12);
            pb0 = *(const float4*)(Brow + k1);
            pb1 = *(const float4*)(Brow + k1 + 4);
            pb2 = *(const float4*)(Brow + k1 + 8);
            pb3 = *(const float4*)(Brow + k1 + 12);
        }
#pragma unroll
        for (int ks = 0; ks < 2; ++ks) {
            bfx8 af = *(const bfx8*)&Ad[(wm + fm) * GSTR + ks * 32 + quad * 8];
#pragma unroll
            for (int j = 0; j < 4; ++j) {
                bfx8 bf = *(const bfx8*)&Bd[(j * 16 + fm) * GSTR + ks * 32 + quad * 8];
                acc[j] = __builtin_amdgcn_mfma_f32_16x16x32_bf16(
                    af, bf, acc[j], 0, 0, 0);
            }
        }
    }

#pragma unroll
    for (int j = 0; j < 4; ++j)
#pragma unroll
        for (int r = 0; r < 4; ++r) {
            int row = m0 + wm + quad * 4 + r;
            int col = n0 + j * 16 + fm;
            if (row < M)
                st_wt_u16(&Out[(size_t)row * TWOD + col],
                          (unsigned)f2h(acc[j][r]));
        }

    // Publish tile-done flag. vmcnt(0) covers THIS thread's stores;
    // __syncthreads makes t0 wait for all threads' waits.
    asm volatile("s_waitcnt vmcnt(0)" ::: "memory");
    __syncthreads();
    if (t == 0)
        __hip_atomic_store(&g_flag[id], G0 + 1, __ATOMIC_RELAXED,
                           __HIP_MEMORY_SCOPE_AGENT);
}

// ---------------------------------------------------------------------------
// Phase C: fused tile, gated on per-tile flags (NOT a global barrier).
// Deps for task (b0,y,z): xh m-tiles {b0/64, b0/64+1} x n-tiles {nt0,nt1}
// (e-slice z*96..z*96+95 spans exactly 2 of the 64-col tiles); plus, for the
// elementwise path (y<3), mh tiles 384 + mt + 3*nt, mt in {0,1,2}.
// y<3: partial[z][b][c] = sum relu(xh+m)*p1 ; y==3: MFMA u-projection.
// ---------------------------------------------------------------------------
__device__ __forceinline__ void phase_fused(
    int id, int G0, char* smem,
    const ushort* __restrict__ xh, const ushort* __restrict__ mh,
    const float* __restrict__ p1w, const float* __restrict__ p2w,
    float* __restrict__ partial)
{
    const int t  = threadIdx.x;
    const int b0 = (id & 7) * 128;
    const int y  = (id >> 3) & 3;
    const int z  = id >> 5;
    const int e0 = z * ECHUNK;

    {   // ---- dataflow gate: poll producer flags (threads 0..9) ----
        const int mt0 = (id & 7) * 2;
        const int nt0 = e0 >> 6;
        const int nt1 = (e0 + ECHUNK - 1) >> 6;
        int depid = -1;
        if (t < 4) {
            depid = (mt0 + (t & 1)) + 16 * ((t >> 1) ? nt1 : nt0);
        } else if (y < 3 && t < 10) {
            const int q = t - 4;
            depid = 384 + (q >> 1) + 3 * ((q & 1) ? nt1 : nt0);
        }
        if (depid >= 0) {
            const int target = G0 + 1;
            while (__hip_atomic_load(&g_flag[depid], __ATOMIC_RELAXED,
                                     __HIP_MEMORY_SCOPE_AGENT) - target < 0)
                __builtin_amdgcn_s_sleep(2);
        }
        asm volatile("" ::: "memory");
        __syncthreads();
    }

    if (y == 3) {
        // -------- MFMA f16 u-projection path --------
        ushort* Au = (ushort*)smem;                 // 128 x USTRU halves
        ushort* Wu = (ushort*)(smem + 30720);       // 64 x USTRU halves
        const int wave = t >> 6, lane = t & 63;
        const int fm = lane & 15, quad = lane >> 4;

        {   // stage relu(xh) f16 : 128 rows x 96 k
            const int row = t >> 1, kh = (t & 1) * 48;
            const ushort* src = xh + (size_t)(b0 + row) * TWOD + e0 + kh;
            uint4 v[6];
#pragma unroll
            for (int i = 0; i < 6; ++i) v[i] = *(const uint4*)&src[i * 8];
#pragma unroll
            for (int i = 0; i < 6; ++i) {
                v[i].x = relu2(v[i].x); v[i].y = relu2(v[i].y);
                v[i].z = relu2(v[i].z); v[i].w = relu2(v[i].w);
                *(uint4*)&Au[row * USTRU + kh + i * 8] = v[i];
            }
        }
        {   // stage p2 (fp32 -> f16) : 64 rows x 96 k
            const int row = t >> 2, ks = (t & 3) * 24;
            const float* pw = p2w + (size_t)row * TWOD + e0 + ks;
#pragma unroll
            for (int i = 0; i < 3; ++i) {
                float4 lo = *(const float4*)&pw[i * 8];
                float4 hi = *(const float4*)&pw[i * 8 + 4];
                *(uint4*)&Wu[row * USTRU + ks + i * 8] = pack_h8(lo, hi);
            }
        }
        __syncthreads();

        f32x4 uacc[2][4];
#pragma unroll
        for (int i = 0; i < 2; ++i)
#pragma unroll
            for (int j = 0; j < 4; ++j) uacc[i][j] = (f32x4){0.f, 0.f, 0.f, 0.f};
#pragma unroll
        for (int k0 = 0; k0 < ECHUNK; k0 += 32) {
            fp16x8 af[2], bff[4];
#pragma unroll
            for (int i = 0; i < 2; ++i)
                af[i] = *(const fp16x8*)&Au[(wave * 32 + i * 16 + fm) * USTRU + k0 + quad * 8];
#pragma unroll
            for (int j = 0; j < 4; ++j)
                bff[j] = *(const fp16x8*)&Wu[(j * 16 + fm) * USTRU + k0 + quad * 8];
#pragma unroll
            for (int i = 0; i < 2; ++i)
#pragma unroll
                for (int j = 0; j < 4; ++j)
                    uacc[i][j] = __builtin_amdgcn_mfma_f32_16x16x32_f16(
                        af[i], bff[j], uacc[i][j], 0, 0, 0);
        }
#pragma unroll
        for (int i = 0; i < 2; ++i)
#pragma unroll
            for (int j = 0; j < 4; ++j)
#pragma unroll
                for (int r = 0; r < 4; ++r) {
                    int row = b0 + wave * 32 + i * 16 + quad * 4 + r;
                    st_wt_f32(&partial[((size_t)z * B_ + row) * CPAD + 192 + j * 16 + fm],
                              uacc[i][j][r]);
                }
        return;
    }

    // -------- elementwise f16 path: cols c0..c0+63 (c0 in {0,64,128}) -----
    unsigned* xT = (unsigned*)smem;             // [48 ep][XSTR] padded words
    unsigned* mT = (unsigned*)(smem + 36864);   // [48][64 c]
    unsigned* wT = (unsigned*)(smem + 49152);   // [48]
    const int c0 = y * 64;
    const int tm = t & 15, tn = t >> 4;

    {   // stage x: 2 thr/row, 48 halves each (padded xT layout)
        const int row = t >> 1, ph = (t & 1) * 48;
        const int rowo = row + ((row >> 3) << 2);
        const ushort* src = xh + (size_t)(b0 + row) * TWOD + e0 + ph;
        uint4 v[6];
#pragma unroll
        for (int i = 0; i < 6; ++i) v[i] = *(const uint4*)&src[i * 8];
#pragma unroll
        for (int i = 0; i < 6; ++i) {
            const int ep = (t & 1) * 24 + i * 4;
            xT[(ep + 0) * XSTR + rowo] = v[i].x;
            xT[(ep + 1) * XSTR + rowo] = v[i].y;
            xT[(ep + 2) * XSTR + rowo] = v[i].z;
            xT[(ep + 3) * XSTR + rowo] = v[i].w;
        }
    }
    {   // stage m: 4 thr/col, 24 halves each
        const int col = t & 63, seg = t >> 6;
        const int gc  = c0 + col;
        uint4 v[3];
        if (gc < C_) {
            const ushort* src = mh + (size_t)gc * TWOD + e0 + seg * 24;
#pragma unroll
            for (int i = 0; i < 3; ++i) v[i] = *(const uint4*)&src[i * 8];
        } else {
#pragma unroll
            for (int i = 0; i < 3; ++i) v[i] = make_uint4(0, 0, 0, 0);
        }
#pragma unroll
        for (int i = 0; i < 3; ++i) {
            const int ep = seg * 12 + i * 4;
            mT[(ep + 0) * 64 + col] = v[i].x;
            mT[(ep + 1) * 64 + col] = v[i].y;
            mT[(ep + 2) * 64 + col] = v[i].z;
            mT[(ep + 3) * 64 + col] = v[i].w;
        }
    }
    if (t < 12) {  // stage w (p1, fp32 -> f16): 96 halves
        float4 lo = *(const float4*)&p1w[e0 + t * 8];
        float4 hi = *(const float4*)&p1w[e0 + t * 8 + 4];
        uint4 v = pack_h8(lo, hi);
        wT[t * 4 + 0] = v.x; wT[t * 4 + 1] = v.y;
        wT[t * 4 + 2] = v.z; wT[t * 4 + 3] = v.w;
    }
    __syncthreads();

    float acc[8][4] = {};
#pragma unroll 4
    for (int ep = 0; ep < 48; ++ep) {
        uint4 a0 = *(const uint4*)&xT[ep * XSTR + tm * 12];
        uint4 a1 = *(const uint4*)&xT[ep * XSTR + tm * 12 + 4];
        uint4 mj = *(const uint4*)&mT[ep * 64 + tn * 4];
        const unsigned wv = wT[ep];
        const unsigned aa[8] = {a0.x, a0.y, a0.z, a0.w, a1.x, a1.y, a1.z, a1.w};
        const unsigned mm[4] = {mj.x, mj.y, mj.z, mj.w};
#pragma unroll
        for (int i = 0; i < 8; ++i)
#pragma unroll
            for (int j = 0; j < 4; ++j)
                acc[i][j] = dot2acc(addrelu2(aa[i], mm[j]), wv, acc[i][j]);
    }

#pragma unroll
    for (int i = 0; i < 8; ++i) {
        const int gb = b0 + tm * 8 + i;
        f32x4 v = {acc[i][0], acc[i][1], acc[i][2], acc[i][3]};
        st_wt_f32x4(&partial[((size_t)z * B_ + gb) * CPAD + c0 + tn * 4], v);
    }
}

// ---------------------------------------------------------------------------
// Phase D: per-row reduce of partials + bias, u-normalize (f16) + cls loss.
// ---------------------------------------------------------------------------
__device__ __forceinline__ void phase_reduce(
    char* smemc,
    const float* __restrict__ partial,
    const float* __restrict__ p1b, const float* __restrict__ p2b,
    const int* __restrict__ lb,
    ushort* __restrict__ uhf, float* __restrict__ sqn,
    float* __restrict__ clsbuf)
{
    float* sval = (float*)smemc;
    const int t = threadIdx.x;
    for (int b = blockIdx.x; b < B_; b += NBLK) {
        float v = 0.f;
#pragma unroll
        for (int z = 0; z < ECHUNKS; ++z)
            v += partial[((size_t)z * B_ + b) * CPAD + t];
        if (t < NCLS)       v += p1b[0];
        else if (t >= 192)  v += p2b[t - 192];

        sval[t] = v;
        __syncthreads();

        if (t < 64) {
            float uv = sval[192 + t];
            float s = uv * uv;
#pragma unroll
            for (int off = 32; off; off >>= 1) s += __shfl_xor(s, off);
            float inv = 1.f / fmaxf(sqrtf(s), 1e-12f);
            st_wt_u16(&uhf[(size_t)b * P_ + t], (unsigned)f2h(uv * inv));
            if (t == 0) st_wt_f32(&sqn[b], s * inv * inv);

            const int l = lb[b];
            float mx = -1e30f;
            for (int j = t; j < NCLS; j += 64)
                if (!(j == l && l < C_)) mx = fmaxf(mx, sval[j]);
#pragma unroll
            for (int off = 32; off; off >>= 1) mx = fmaxf(mx, __shfl_xor(mx, off));
            float se = 0.f;
            for (int j = t; j < NCLS; j += 64)
                if (!(j == l && l < C_)) se += expf(sval[j] - mx);
#pragma unroll
            for (int off = 32; off; off >>= 1) se += __shfl_xor(se, off);

            if (t == 0) {
                float l150  = sval[C_];
                float loss2 = mx + logf(se) - l150;
                float loss1 = 0.f;
                if (l < C_) {
                    float a  = sval[l];
                    float m2 = fmaxf(a, l150);
                    loss1 = m2 - a + logf(expf(a - m2) + expf(l150 - m2));
                }
                st_wt_f32(&clsbuf[b], loss1 + loss2);
            }
        }
        __syncthreads();
    }
}

// ---------------------------------------------------------------------------
// Phase E: pairwise margin losses via f16 MFMA Gram tiles. 256 tasks.
// ---------------------------------------------------------------------------
__device__ __forceinline__ void phase_pair(
    int id, char* smemc,
    const ushort* __restrict__ uhf, const float* __restrict__ sqn,
    const int* __restrict__ lb, float* __restrict__ pairpart)
{
    ushort* ui_s = (ushort*)smemc;               // 64*USTR halves = 9216 B
    ushort* uj_s = (ushort*)(smemc + 9216);      // 9216 B
    float*  sni  = (float*)(smemc + 18432);
    float*  snj  = (float*)(smemc + 18688);
    int*    li   = (int*)(smemc + 18944);
    int*    lj   = (int*)(smemc + 19200);
    float*  red  = (float*)(smemc + 19456);      // [4][4]

    const int t  = threadIdx.x;
    const int i0 = (id & 15) * 64, j0 = (id >> 4) * 64;

    for (int idx = t; idx < 512; idx += 256) {
        int row = idx >> 3, ch = (idx & 7) * 8;
        *(uint4*)&ui_s[row * USTR + ch] =
            *(const uint4*)&uhf[(size_t)(i0 + row) * P_ + ch];
        *(uint4*)&uj_s[row * USTR + ch] =
            *(const uint4*)&uhf[(size_t)(j0 + row) * P_ + ch];
    }
    if (t < 64)       { sni[t] = sqn[i0 + t]; li[t] = lb[i0 + t]; }
    else if (t < 128) { int q = t - 64; snj[q] = sqn[j0 + q]; lj[q] = lb[j0 + q]; }
    __syncthreads();

    const int wave = t >> 6, lane = t & 63;
    const int n = lane & 15, quad = lane >> 4;
    const int iw = wave * 16;

    const fp16x8 af0 = *(const fp16x8*)&ui_s[(iw + n) * USTR + quad * 8];
    const fp16x8 af1 = *(const fp16x8*)&ui_s[(iw + n) * USTR + quad * 8 + 32];

    f32x4 acc[4];
#pragma unroll
    for (int jt = 0; jt < 4; ++jt) {
        const fp16x8 bf0 = *(const fp16x8*)&uj_s[(jt * 16 + n) * USTR + quad * 8];
        const fp16x8 bf1 = *(const fp16x8*)&uj_s[(jt * 16 + n) * USTR + quad * 8 + 32];
        acc[jt] = __builtin_amdgcn_mfma_f32_16x16x32_f16(
            af0, bf0, (f32x4){0.f, 0.f, 0.f, 0.f}, 0, 0, 0);
        acc[jt] = __builtin_amdgcn_mfma_f32_16x16x32_f16(
            af1, bf1, acc[jt], 0, 0, 0);
    }

    float ps = 0.f, pc = 0.f, ns = 0.f, nc = 0.f;
#pragma unroll
    for (int jt = 0; jt < 4; ++jt)
#pragma unroll
        for (int r = 0; r < 4; ++r) {
            const int il = iw + quad * 4 + r;
            const int jl = jt * 16 + n;
            float sq = sni[il] + snj[jl] - 2.f * acc[jt][r];
            float dist = sq > 0.f ? sqrtf(fmaxf(sq, 1e-16f)) : 0.f;
            bool same = (li[il] == lj[jl]);
            if (same) {
                if (i0 + il != j0 + jl) { ps += fmaxf(dist - 0.7f, 0.f); pc += 1.f; }
            } else {
                ns += fmaxf(1.4f - dist, 0.f); nc += 1.f;
            }
        }

#pragma unroll
    for (int off = 32; off; off >>= 1) {
        ps += __shfl_xor(ps, off); pc += __shfl_xor(pc, off);
        ns += __shfl_xor(ns, off); nc += __shfl_xor(nc, off);
    }
    if (lane == 0) { red[0 * 4 + wave] = ps; red[1 * 4 + wave] = pc;
                     red[2 * 4 + wave] = ns; red[3 * 4 + wave] = nc; }
    __syncthreads();
    if (t == 0) {
        f32x4 v;
        v[0] = red[0] + red[1] + red[2] + red[3];
        v[1] = red[4] + red[5] + red[6] + red[7];
        v[2] = red[8] + red[9] + red[10] + red[11];
        v[3] = red[12] + red[13] + red[14] + red[15];
        st_wt_f32x4(&pairpart[(size_t)id * 4], v);
    }
}

// ---------------------------------------------------------------------------
// Phase F: block 0 reduces clsbuf[1024] and pairpart[256][4] -> out[0].
// ---------------------------------------------------------------------------
__device__ __forceinline__ void phase_final(
    char* smemc,
    const float* __restrict__ clsbuf, const float* __restrict__ pairpart,
    float* __restrict__ out)
{
    float* red = (float*)smemc;   // [5][4]
    const int t = threadIdx.x;
    float c = clsbuf[t] + clsbuf[t + 256] + clsbuf[t + 512] + clsbuf[t + 768];
    float4 pp = *(const float4*)&pairpart[(size_t)t * 4];
    float ps = pp.x, pc = pp.y, ns = pp.z, nc = pp.w;
#pragma unroll
    for (int off = 32; off; off >>= 1) {
        c  += __shfl_xor(c, off);
        ps += __shfl_xor(ps, off); pc += __shfl_xor(pc, off);
        ns += __shfl_xor(ns, off); nc += __shfl_xor(nc, off);
    }
    const int wave = t >> 6, lane = t & 63;
    if (lane == 0) { red[0 * 4 + wave] = c; red[1 * 4 + wave] = ps;
                     red[2 * 4 + wave] = pc; red[3 * 4 + wave] = ns;
                     red[4 * 4 + wave] = nc; }
    __syncthreads();
    if (t == 0) {
        float C = 0.f, PS = 0.f, PC = 0.f, NS = 0.f, NC = 0.f;
#pragma unroll
        for (int w = 0; w < 4; ++w) {
            C += red[0 * 4 + w]; PS += red[1 * 4 + w]; PC += red[2 * 4 + w];
            NS += red[3 * 4 + w]; NC += red[4 * 4 + w];
        }
        out[0] = C / (float)B_ + PS / fmaxf(PC, 1.f) + NS / fmaxf(NC, 1.f);
    }
}

// ---------------------------------------------------------------------------
// Persistent mega-kernel: 512 blocks x 256 threads, 2 blocks/CU co-resident.
// B->C edge is dataflow (per-tile flags, overlapped); barriers: C->D (1),
// D->E (2), final arrive-only (3). gen advances by 3 per launch.
// ---------------------------------------------------------------------------
__global__ __launch_bounds__(256, 2) void mega(
    const float* __restrict__ x, const int* __restrict__ lb,
    const float* __restrict__ mem, const float* __restrict__ fc_w,
    const float* __restrict__ fc_b, const float* __restrict__ p1w,
    const float* __restrict__ p1b, const float* __restrict__ p2w,
    const float* __restrict__ p2b,
    float* ws, float* out)
{
    __shared__ __align__(16) char smem[49344];
    __shared__ int G0s;

    ushort* mh       = (ushort*)(ws + OFF_MH);
    ushort* xh       = (ushort*)(ws + OFF_XH);
    float*  partial  = ws + OFF_PARTIAL;
    ushort* uhf      = (ushort*)(ws + OFF_UHF);
    float*  sqn      = ws + OFF_SQN;
    float*  clsbuf   = ws + OFF_CLS;
    float*  pairpart = ws + OFF_PAIR;

    const int id = blockIdx.x;

    // Entry read of the monotonic epoch, broadcast to all threads. Safe:
    // gen cannot advance past its pre-launch value until this block itself
    // participates; the flag/arrival values derive from G0 (data dep).
    if (threadIdx.x == 0) {
        G0s = __hip_atomic_load(&g_gen[(blockIdx.x & 31) * 16],
                                __ATOMIC_RELAXED, __HIP_MEMORY_SCOPE_AGENT);
    }
    __syncthreads();
    const int G0 = G0s;

    phase_gemm(id, G0, smem, x, mem, fc_w, fc_b, xh, mh);
    // no global barrier: B->C is dataflow-gated inside phase_fused
    phase_fused(id, G0, smem, xh, mh, p1w, p2w, partial);
    grid_barrier(G0, 1);
    phase_reduce(smem, partial, p1b, p2b, lb, uhf, sqn, clsbuf);
    grid_barrier(G0, 2);
    if (id < 256) phase_pair(id, smem, uhf, sqn, lb, pairpart);

    // ---- barrier 3 (arrive-only, monotonic) + root-runs-final ----
    asm volatile("s_waitcnt vmcnt(0)" ::: "memory");
    __syncthreads();
    if (threadIdx.x == 0) {
        __hip_atomic_fetch_add(&g_arr[(blockIdx.x & 7) * 16], 1,
                               __ATOMIC_RELAXED, __HIP_MEMORY_SCOPE_AGENT);
    }
    if (blockIdx.x == 0) {
        if (threadIdx.x == 0) {
            const int starget = NBLK * (G0 + 3);
            for (;;) {
                int s = 0;
#pragma unroll
                for (int k = 0; k < 8; ++k)
                    s += __hip_atomic_load(&g_arr[k * 16], __ATOMIC_RELAXED,
                                           __HIP_MEMORY_SCOPE_AGENT);
                if (s - starget >= 0) break;
                __builtin_amdgcn_s_sleep(1);
            }
            // Advance gen so the NEXT launch's entry reads see G0+3.
#pragma unroll
            for (int r = 0; r < 32; ++r)
                __hip_atomic_store(&g_gen[r * 16], G0 + 3, __ATOMIC_RELAXED,
                                   __HIP_MEMORY_SCOPE_AGENT);
        }
        asm volatile("" ::: "memory");
        __syncthreads();
        phase_final(smem, clsbuf, pairpart, out);
    }
}

extern "C" void kernel_launch(void* const* d_in, const int* in_sizes, int n_in,
                              void* d_out, int out_size, void* d_ws, size_t ws_size,
                              hipStream_t stream)
{
    const float* x    = (const float*)d_in[0];
    const int*   lb   = (const int*)d_in[1];
    const float* mem  = (const float*)d_in[2];
    const float* fc_w = (const float*)d_in[3];
    const float* fc_b = (const float*)d_in[4];
    const float* p1w  = (const float*)d_in[5];
    const float* p1b  = (const float*)d_in[6];
    const float* p2w  = (const float*)d_in[7];
    const float* p2b  = (const float*)d_in[8];

    float* ws = (float*)d_ws;

    mega<<<NBLK, 256, 0, stream>>>(x, lb, mem, fc_w, fc_b,
                                   p1w, p1b, p2w, p2b, ws, (float*)d_out);
}